// Round 1
// baseline (137.068 us; speedup 1.0000x reference)
//
#include <hip/hip_runtime.h>

// TotalDegree: out[b, i] = prod over multiset term i of x[b, d], terms = all
// multisets of size 0..4 over 8 vars, sorted lexicographically (tuple order).
// Factorization: every term = P[u] * P[v] where P = the 45 multisets of size
// <= 2 (empty=1, singles x_d, pairs x_i*x_j). P lives one-per-lane in a wave;
// terms are fetched with two ds_bpermute (__shfl) and one multiply.

struct Specs {
    unsigned short uv[8][64];  // per chunk c (terms c*64+lane): u | (v<<8)
    unsigned short pp[64];     // per lane: s1 | s2<<4 | use1<<8 | use2<<9
};

constexpr int pidx_c(int a, int b) {
    // pair (a,b), a<=b -> lane index 9..44 (empty=0, singles=1..8)
    return 9 + 8 * a - (a * (a - 1)) / 2 + (b - a);
}

constexpr Specs make_specs() {
    Specs S{};
    // Per-lane pair-product spec: which x elements lane l multiplies for P[l].
    for (int l = 0; l < 64; ++l) {
        int s1 = 0, s2 = 0, u1 = 0, u2 = 0;
        if (l >= 1 && l <= 8) { s1 = l - 1; u1 = 1; }
        else if (l >= 9 && l < 45) {
            int k = l - 9, i = 0;
            while (k >= 8 - i) { k -= 8 - i; ++i; }
            s1 = i; s2 = i + k; u1 = 1; u2 = 1;
        }
        S.pp[l] = (unsigned short)(s1 | (s2 << 4) | (u1 << 8) | (u2 << 9));
    }
    // DFS preorder over non-decreasing tuples == lexicographic sorted order
    // used by the reference. Term index -> (u, v) lane indices into P.
    int idx = 1;  // index 0 = empty term: uv = 0|0 (zero-init)
    for (int a = 0; a < 8; ++a) {
        S.uv[idx >> 6][idx & 63] = (unsigned short)(1 + a); ++idx;              // (a)
        for (int b = a; b < 8; ++b) {
            S.uv[idx >> 6][idx & 63] = (unsigned short)pidx_c(a, b); ++idx;     // (a,b)
            for (int c = b; c < 8; ++c) {
                S.uv[idx >> 6][idx & 63] =
                    (unsigned short)(pidx_c(a, b) | ((1 + c) << 8)); ++idx;     // (a,b,c)
                for (int d = c; d < 8; ++d) {
                    S.uv[idx >> 6][idx & 63] =
                        (unsigned short)(pidx_c(a, b) | (pidx_c(c, d) << 8));   // (a,b,c,d)
                    ++idx;
                }
            }
        }
    }
    // idx == 495 here; uv[7][47..63] stay zero (stores masked for t >= 495).
    return S;
}

__constant__ Specs SPECS = make_specs();

__global__ __launch_bounds__(64) void TotalDegree_29755533426739_kernel(
    const float* __restrict__ x, float* __restrict__ out, int B, int rows_per_wave) {
    const int lane = (int)threadIdx.x;

    // Per-lane constants (row-invariant): pair-product sources + term specs.
    const int ppv  = SPECS.pp[lane];
    const int s1   = ppv & 15;
    const int s2   = (ppv >> 4) & 15;
    const bool use1 = ((ppv >> 8) & 1) != 0;
    const bool use2 = ((ppv >> 9) & 1) != 0;

    int uspec[8], vspec[8];
    #pragma unroll
    for (int c = 0; c < 8; ++c) {
        const int sp = (int)SPECS.uv[c][lane];
        uspec[c] = sp & 255;
        vspec[c] = sp >> 8;
    }

    int row0 = (int)blockIdx.x * rows_per_wave;
    int row1 = row0 + rows_per_wave;
    if (row1 > B) row1 = B;

    for (int row = row0; row < row1; ++row) {
        const float* x8 = x + (size_t)row * 8;
        const float a1 = x8[s1];            // gather inside one 32B line (L1)
        const float a2 = x8[s2];
        const float P  = (use1 ? a1 : 1.0f) * (use2 ? a2 : 1.0f);  // P[lane]

        float* orow = out + (size_t)row * 495;
        #pragma unroll
        for (int c = 0; c < 8; ++c) {
            const float f1 = __shfl(P, uspec[c], 64);
            const float f2 = __shfl(P, vspec[c], 64);
            const float tv = f1 * f2;
            const int t = c * 64 + lane;
            if (t < 495) orow[t] = tv;      // lane-consecutive -> coalesced
        }
    }
}

extern "C" void kernel_launch(void* const* d_in, const int* in_sizes, int n_in,
                              void* d_out, int out_size, void* d_ws, size_t ws_size,
                              hipStream_t stream) {
    const float* x = (const float*)d_in[0];
    float* out = (float*)d_out;
    const int B = in_sizes[0] / 8;          // 65536 rows of dim 8
    const int ROWS = 16;                    // rows per wave
    const int grid = (B + ROWS - 1) / ROWS; // 4096 one-wave blocks
    hipLaunchKernelGGL(TotalDegree_29755533426739_kernel,
                       dim3(grid), dim3(64), 0, stream, x, out, B, ROWS);
}

// Round 2
// 131.621 us; speedup vs baseline: 1.0414x; 1.0414x over previous
//
#include <hip/hip_runtime.h>

// TotalDegree: out[b, t] = prod over multiset term t of x[b, d]; terms = all
// multisets of size 0..4 over 8 vars in lexicographic (sorted-tuple) order.
// Factorization: term = P[u]*P[v], P = 45 multisets of size <= 2, one per lane.
// R1: stage x through LDS (bulk coalesced load, kills per-row global-gather
// latency), 256-thread blocks (16 waves/CU at <=128 VGPR), row loop unroll x2,
// spec table transposed so per-lane init is one 16B load.

struct Specs {
    unsigned short uv[64][8];  // [lane][chunk]: u | (v<<8) for term c*64+lane
    unsigned short pp[64];     // per lane: s1 | s2<<4 | use1<<8 | use2<<9
};

constexpr int pidx_c(int a, int b) {
    return 9 + 8 * a - (a * (a - 1)) / 2 + (b - a);  // pair lane, empty=0, singles=1..8
}

constexpr Specs make_specs() {
    Specs S{};
    for (int l = 0; l < 64; ++l) {
        int s1 = 0, s2 = 0, u1 = 0, u2 = 0;
        if (l >= 1 && l <= 8) { s1 = l - 1; u1 = 1; }
        else if (l >= 9 && l < 45) {
            int k = l - 9, i = 0;
            while (k >= 8 - i) { k -= 8 - i; ++i; }
            s1 = i; s2 = i + k; u1 = 1; u2 = 1;
        }
        S.pp[l] = (unsigned short)(s1 | (s2 << 4) | (u1 << 8) | (u2 << 9));
    }
    // DFS preorder over non-decreasing tuples == reference's sorted order.
    int idx = 1;  // term 0 = empty: u=v=0 -> P[0]*P[0]=1
    for (int a = 0; a < 8; ++a) {
        S.uv[idx & 63][idx >> 6] = (unsigned short)(1 + a); ++idx;
        for (int b = a; b < 8; ++b) {
            S.uv[idx & 63][idx >> 6] = (unsigned short)pidx_c(a, b); ++idx;
            for (int c = b; c < 8; ++c) {
                S.uv[idx & 63][idx >> 6] =
                    (unsigned short)(pidx_c(a, b) | ((1 + c) << 8)); ++idx;
                for (int d = c; d < 8; ++d) {
                    S.uv[idx & 63][idx >> 6] =
                        (unsigned short)(pidx_c(a, b) | (pidx_c(c, d) << 8));
                    ++idx;
                }
            }
        }
    }
    return S;  // idx == 495; terms 495..511 stay 0, stores masked
}

__constant__ Specs SPECS = make_specs();

#define ROWS_PER_BLOCK 32
#define ROWS_PER_WAVE  8

__global__ __launch_bounds__(256, 4) void TotalDegree_29755533426739_kernel(
    const float* __restrict__ x, float* __restrict__ out, int B) {
    __shared__ float xs[ROWS_PER_BLOCK * 8];  // 1 KB x-tile

    const int tid  = (int)threadIdx.x;
    const int lane = tid & 63;
    const int wid  = tid >> 6;

    // Bulk coalesced x-tile load: 256 threads x 4 B = 1 KB = 32 rows.
    {
        const int gi = (int)blockIdx.x * (ROWS_PER_BLOCK * 8) + tid;
        xs[tid] = (gi < B * 8) ? x[gi] : 0.0f;
    }

    // Per-lane constants (row-invariant).
    const int ppv  = (int)SPECS.pp[lane];
    const int s1   = ppv & 15;
    const int s2   = (ppv >> 4) & 15;
    const bool use1 = ((ppv >> 8) & 1) != 0;
    const bool use2 = ((ppv >> 9) & 1) != 0;

    int uspec[8], vspec[8];
    #pragma unroll
    for (int c = 0; c < 8; ++c) {
        const int sp = (int)SPECS.uv[lane][c];  // contiguous 16 B/lane
        uspec[c] = sp & 255;
        vspec[c] = sp >> 8;
    }

    __syncthreads();

    #pragma unroll 2
    for (int rr = 0; rr < ROWS_PER_WAVE; ++rr) {
        const int r    = wid * ROWS_PER_WAVE + rr;
        const int grow = (int)blockIdx.x * ROWS_PER_BLOCK + r;
        if (grow < B) {
            const float a1 = xs[r * 8 + s1];   // 8 distinct words, bank-broadcast
            const float a2 = xs[r * 8 + s2];
            const float P  = (use1 ? a1 : 1.0f) * (use2 ? a2 : 1.0f);

            float* orow = out + (size_t)grow * 495;
            #pragma unroll
            for (int c = 0; c < 8; ++c) {
                const float f1 = __shfl(P, uspec[c], 64);
                const float f2 = __shfl(P, vspec[c], 64);
                const int t = c * 64 + lane;
                if (t < 495) orow[t] = f1 * f2;  // lane-consecutive, coalesced
            }
        }
    }
}

extern "C" void kernel_launch(void* const* d_in, const int* in_sizes, int n_in,
                              void* d_out, int out_size, void* d_ws, size_t ws_size,
                              hipStream_t stream) {
    const float* x = (const float*)d_in[0];
    float* out = (float*)d_out;
    const int B = in_sizes[0] / 8;  // 65536 rows
    const int grid = (B + ROWS_PER_BLOCK - 1) / ROWS_PER_BLOCK;  // 2048
    hipLaunchKernelGGL(TotalDegree_29755533426739_kernel,
                       dim3(grid), dim3(256), 0, stream, x, out, B);
}

// Round 3
// 129.885 us; speedup vs baseline: 1.0553x; 1.0134x over previous
//
#include <hip/hip_runtime.h>

// TotalDegree: out[b, t] = prod over multiset term t of x[b, d]; terms = all
// multisets of size 0..4 over 8 vars in lexicographic (sorted-tuple) order.
// Factorization: term = P[u]*P[v], P = 45 multisets of size <= 2, one per lane.
// R2: kernel is ~50us vs 21us write floor (bench dur includes ~80us harness
// poison fill). Fixes: 32 waves/CU (launch_bounds(256,8), lean VGPR), 32-bit
// offset stores (8 chunk stores share one addr reg + imm offsets 0..1792),
// pre-scaled ds_bpermute byte addresses, compile-time tail predication.

struct Specs {
    unsigned short uv[64][8];  // [lane][chunk]: u | (v<<8) for term c*64+lane
    unsigned short pp[64];     // per lane: s1 | s2<<4 | use1<<8 | use2<<9
};

constexpr int pidx_c(int a, int b) {
    return 9 + 8 * a - (a * (a - 1)) / 2 + (b - a);  // empty=0, singles=1..8, pairs 9..44
}

constexpr Specs make_specs() {
    Specs S{};
    for (int l = 0; l < 64; ++l) {
        int s1 = 0, s2 = 0, u1 = 0, u2 = 0;
        if (l >= 1 && l <= 8) { s1 = l - 1; u1 = 1; }
        else if (l >= 9 && l < 45) {
            int k = l - 9, i = 0;
            while (k >= 8 - i) { k -= 8 - i; ++i; }
            s1 = i; s2 = i + k; u1 = 1; u2 = 1;
        }
        S.pp[l] = (unsigned short)(s1 | (s2 << 4) | (u1 << 8) | (u2 << 9));
    }
    // DFS preorder over non-decreasing tuples == reference's sorted order.
    int idx = 1;  // term 0 = empty: u=v=0 -> P[0]*P[0] = 1
    for (int a = 0; a < 8; ++a) {
        S.uv[idx & 63][idx >> 6] = (unsigned short)(1 + a); ++idx;
        for (int b = a; b < 8; ++b) {
            S.uv[idx & 63][idx >> 6] = (unsigned short)pidx_c(a, b); ++idx;
            for (int c = b; c < 8; ++c) {
                S.uv[idx & 63][idx >> 6] =
                    (unsigned short)(pidx_c(a, b) | ((1 + c) << 8)); ++idx;
                for (int d = c; d < 8; ++d) {
                    S.uv[idx & 63][idx >> 6] =
                        (unsigned short)(pidx_c(a, b) | (pidx_c(c, d) << 8));
                    ++idx;
                }
            }
        }
    }
    return S;  // idx == 495; terms 495..511 stay 0, chunk-7 stores masked
}

__constant__ Specs SPECS = make_specs();

#define WAVES_PER_BLOCK 4
#define ROWS_PER_WAVE   8
#define ROWS_PER_BLOCK  (WAVES_PER_BLOCK * ROWS_PER_WAVE)  // 32

__global__ __launch_bounds__(256, 8) void TotalDegree_29755533426739_kernel(
    const float* __restrict__ x, float* __restrict__ out, int B) {
    __shared__ float xs[ROWS_PER_BLOCK * 8];  // 1 KB x-tile

    const int tid  = (int)threadIdx.x;
    const int lane = tid & 63;
    const int wid  = tid >> 6;

    // Bulk coalesced x-tile load: 256 threads x 4 B = 32 rows.
    {
        const int gi = (int)blockIdx.x * (ROWS_PER_BLOCK * 8) + tid;
        xs[tid] = (gi < B * 8) ? x[gi] : 0.0f;
    }

    // Per-lane row-invariant constants.
    const int ppv  = (int)SPECS.pp[lane];
    const int s1   = ppv & 15;
    const int s2   = (ppv >> 4) & 15;
    const bool use1 = ((ppv >> 8) & 1) != 0;
    const bool use2 = ((ppv >> 9) & 1) != 0;

    int u4[8], v4[8];  // pre-scaled bpermute byte addresses (lane*4)
    #pragma unroll
    for (int c = 0; c < 8; ++c) {
        const int sp = (int)SPECS.uv[lane][c];  // contiguous 16 B per lane
        u4[c] = (sp & 255) << 2;
        v4[c] = (sp >> 8) << 2;
    }

    __syncthreads();

    const float* xw = xs + wid * (ROWS_PER_WAVE * 8);  // this wave's rows
    const unsigned baseRow =
        (unsigned)blockIdx.x * ROWS_PER_BLOCK + (unsigned)(wid * ROWS_PER_WAVE);
    unsigned off = baseRow * 495u + (unsigned)lane;  // 32-bit elem offset

    #pragma unroll 2
    for (int rr = 0; rr < ROWS_PER_WAVE; ++rr) {
        const float a1 = xw[rr * 8 + s1];  // <=8 words, consecutive banks + bcast
        const float a2 = xw[rr * 8 + s2];
        const float P  = (use1 ? a1 : 1.0f) * (use2 ? a2 : 1.0f);
        const int  Pi  = __float_as_int(P);

        #pragma unroll
        for (int c = 0; c < 8; ++c) {
            const float f1 = __int_as_float(__builtin_amdgcn_ds_bpermute(u4[c], Pi));
            const float f2 = __int_as_float(__builtin_amdgcn_ds_bpermute(v4[c], Pi));
            const float tv = f1 * f2;
            if (c < 7) {
                out[off + (unsigned)(c * 64)] = tv;   // imm offsets 0..1536
            } else if (lane < 47) {                   // terms 448..494
                out[off + 448u] = tv;
            }
        }
        off += 495u;
    }
}

extern "C" void kernel_launch(void* const* d_in, const int* in_sizes, int n_in,
                              void* d_out, int out_size, void* d_ws, size_t ws_size,
                              hipStream_t stream) {
    const float* x = (const float*)d_in[0];
    float* out = (float*)d_out;
    const int B = in_sizes[0] / 8;  // 65536 rows
    const int grid = (B + ROWS_PER_BLOCK - 1) / ROWS_PER_BLOCK;  // 2048
    hipLaunchKernelGGL(TotalDegree_29755533426739_kernel,
                       dim3(grid), dim3(256), 0, stream, x, out, B);
}